// Round 1
// baseline (560.083 us; speedup 1.0000x reference)
//
#include <hip/hip_runtime.h>

// PPNet forward on MI355X. bf16 MFMA GEMMs (16x16x32), fp32 accumulate.
// Pipeline per layer: A(mode0 h_pre + BN stats) -> bn_finalize -> G1(mode1) -> C(mode2 gate+BN+relu).
// All D=4 domains computed for all B=32768 rows (BN stats need full batch per domain).

typedef __attribute__((ext_vector_type(8))) short short8;
typedef __attribute__((ext_vector_type(4))) float floatx4;

#define BATCH 32768
#define NDOM 4
#define TM 128
#define TN 64
#define KSTEP 32
#define LDA 40  // 32 bf16 + 8 pad per LDS row -> <=2-way bank aliasing (free)

__device__ __forceinline__ unsigned short f2b(float f) {
    unsigned u = __float_as_uint(f);
    u += 0x7fffu + ((u >> 16) & 1u);  // round-to-nearest-even
    return (unsigned short)(u >> 16);
}
__device__ __forceinline__ float b2f(unsigned short h) {
    return __uint_as_float(((unsigned)h) << 16);
}

// ---------------------------------------------------------------------------
// Weight prep: fp32 (D,K,N) -> bf16 (D,N,K) [transposed so B-operand fragment
// loads are 8 contiguous bf16], packed back-to-back in ws. Also zeroes the
// BN stat accumulators (harness poisons ws each call).
struct MatDesc { const float* src; unsigned K, N, pfx, total; };
struct PrepArgs { MatDesc m[9]; float* stats; unsigned statsN; unsigned grand; };

__global__ __launch_bounds__(256) void prep_k(PrepArgs a, unsigned short* __restrict__ wt) {
    unsigned e = blockIdx.x * 256 + threadIdx.x;
    if (e < a.statsN) a.stats[e] = 0.f;
    if (e >= a.grand) return;
    int j = 0;
    while (j < 8 && e >= a.m[j].pfx + a.m[j].total) j++;
    const unsigned K = a.m[j].K, N = a.m[j].N;
    const unsigned local = e - a.m[j].pfx;
    const unsigned kn = K * N;
    const unsigned d = local / kn;
    const unsigned r2 = local - d * kn;
    const unsigned n = r2 / K;
    const unsigned k = r2 - n * K;
    wt[e] = f2b(a.m[j].src[((long long)d * K + k) * N + n]);
}

// ---------------------------------------------------------------------------
// Embedding gather: gate_in[b, 0:128] = id emb, [128:256] = agn emb, as bf16.
__global__ __launch_bounds__(256) void embed_k(const int* __restrict__ idi, const int* __restrict__ agi,
                                               const float* __restrict__ idt, const float* __restrict__ agt,
                                               unsigned short* __restrict__ gin) {
    int t = blockIdx.x * 256 + threadIdx.x;  // B*16 threads, one per (b, 16-elem slot)
    int b = t >> 4, slot = t & 15;
    int f = slot & 7;
    const int* ip = (slot < 8) ? idi : agi;
    const float* tab = (slot < 8) ? idt : agt;
    int ix = ip[b * 8 + f];
    const float* src = tab + ((long long)f * 100000 + ix) * 16;
    unsigned short tmp[16];
#pragma unroll
    for (int j = 0; j < 16; j++) tmp[j] = f2b(src[j]);
    unsigned short* dst = gin + (long long)b * 256 + slot * 16;
    *(uint4*)dst = *(const uint4*)tmp;
    *(uint4*)(dst + 8) = *(const uint4*)(tmp + 8);
}

// ---------------------------------------------------------------------------
// GEMM: out[d, m0:m0+128, n0:n0+64] = X[d?] (M x K, bf16) @ Wt[d] (N x K, bf16)^T + bias
// mode 0: store h_pre (fp32 if hf32 else bf16) + accumulate per-(d,n) sum/sumsq
// mode 1: relu, store bf16
// mode 2: gate = 2*sigmoid(acc+bias); h = hpre; out = relu((h-mu)*rs*g + b)*gate, bf16
__global__ __launch_bounds__(256) void gemm_ep(
    const unsigned short* __restrict__ X, long long xds,
    const unsigned short* __restrict__ Wt,
    const float* __restrict__ bias,
    void* outv,
    int N, int K, int mode, int hf32,
    const void* hprev,
    const float* __restrict__ muv, const float* __restrict__ rsv,
    const float* __restrict__ gma, const float* __restrict__ bta,
    float* __restrict__ gsum, float* __restrict__ gssq) {
    __shared__ __align__(16) unsigned short sA[TM * LDA];
    __shared__ __align__(16) unsigned short sB[TN * LDA];
    __shared__ float sSum[TN], sSsq[TN];

    const int t = threadIdx.x;
    const int d = blockIdx.z;
    const int m0 = blockIdx.x * TM, n0 = blockIdx.y * TN;
    const unsigned short* Xp = X + (long long)d * xds + (long long)m0 * K;
    const unsigned short* Wp = Wt + ((long long)d * N + n0) * (long long)K;

    floatx4 acc[2][4];
#pragma unroll
    for (int i = 0; i < 2; i++)
#pragma unroll
        for (int j = 0; j < 4; j++) acc[i][j] = (floatx4)(0.0f);

    const int w = t >> 6, lane = t & 63, lrow = lane & 15, lq = lane >> 4;
    const int arow = t >> 2, ach = t & 3;  // staging: 16B per thread per row-chunk

    for (int k0 = 0; k0 < K; k0 += KSTEP) {
        *(uint4*)&sA[arow * LDA + ach * 8] = *(const uint4*)&Xp[(long long)arow * K + k0 + ach * 8];
        *(uint4*)&sA[(arow + 64) * LDA + ach * 8] = *(const uint4*)&Xp[(long long)(arow + 64) * K + k0 + ach * 8];
        *(uint4*)&sB[arow * LDA + ach * 8] = *(const uint4*)&Wp[(long long)arow * K + k0 + ach * 8];
        __syncthreads();
        short8 a[2], b[4];
#pragma unroll
        for (int rt = 0; rt < 2; rt++)
            a[rt] = *(const short8*)&sA[(w * 32 + rt * 16 + lrow) * LDA + lq * 8];
#pragma unroll
        for (int ct = 0; ct < 4; ct++)
            b[ct] = *(const short8*)&sB[(ct * 16 + lrow) * LDA + lq * 8];
#pragma unroll
        for (int rt = 0; rt < 2; rt++)
#pragma unroll
            for (int ct = 0; ct < 4; ct++)
                acc[rt][ct] = __builtin_amdgcn_mfma_f32_16x16x32_bf16(a[rt], b[ct], acc[rt][ct], 0, 0, 0);
        __syncthreads();
    }

    if (mode == 0) {
        if (t < TN) { sSum[t] = 0.f; sSsq[t] = 0.f; }
        __syncthreads();
    }

    const long long orow = (long long)d * BATCH + m0;
#pragma unroll
    for (int ct = 0; ct < 4; ct++) {
        const int nl = ct * 16 + lrow;
        const int n = n0 + nl;
        const float bs = bias[d * N + n];
        float mu_ = 0.f, sc_ = 0.f, bb_ = 0.f;
        if (mode == 2) {
            mu_ = muv[d * N + n];
            sc_ = rsv[d * N + n] * gma[d * N + n];
            bb_ = bta[d * N + n];
        }
        float s = 0.f, ss = 0.f;
#pragma unroll
        for (int rt = 0; rt < 2; rt++) {
            const int mb = w * 32 + rt * 16 + lq * 4;
#pragma unroll
            for (int r = 0; r < 4; r++) {
                float v = acc[rt][ct][r] + bs;
                const long long oi = (orow + mb + r) * (long long)N + n;
                if (mode == 0) {
                    s += v; ss += v * v;
                    if (hf32) ((float*)outv)[oi] = v;
                    else ((unsigned short*)outv)[oi] = f2b(v);
                } else if (mode == 1) {
                    v = fmaxf(v, 0.f);
                    ((unsigned short*)outv)[oi] = f2b(v);
                } else {
                    const float gate = 2.f / (1.f + __expf(-v));
                    const float h = hf32 ? ((const float*)hprev)[oi] : b2f(((const unsigned short*)hprev)[oi]);
                    float x = (h - mu_) * sc_ + bb_;
                    x = fmaxf(x, 0.f);
                    ((unsigned short*)outv)[oi] = f2b(x * gate);
                }
            }
        }
        if (mode == 0) {
            // reduce lanes {l, l+16, l+32, l+48} (same output column)
            s += __shfl_down(s, 32); ss += __shfl_down(ss, 32);
            s += __shfl_down(s, 16); ss += __shfl_down(ss, 16);
            if (lane < 16) {
                atomicAdd(&sSum[nl], s);
                atomicAdd(&sSsq[nl], ss);
            }
        }
    }
    if (mode == 0) {
        __syncthreads();
        if (t < TN) {
            atomicAdd(&gsum[d * N + n0 + t], sSum[t]);
            atomicAdd(&gssq[d * N + n0 + t], sSsq[t]);
        }
    }
}

// ---------------------------------------------------------------------------
__global__ void bn_finalize(const float* __restrict__ gsum, const float* __restrict__ gssq,
                            float* __restrict__ muv, float* __restrict__ rsv, int total, float invB) {
    int i = blockIdx.x * blockDim.x + threadIdx.x;
    if (i >= total) return;
    float mu = gsum[i] * invB;
    float var = gssq[i] * invB - mu * mu;
    muv[i] = mu;
    rsv[i] = rsqrtf(var + 1e-5f);
}

// ---------------------------------------------------------------------------
__global__ __launch_bounds__(256) void final_k(const unsigned short* __restrict__ X3, const int* __restrict__ dom,
                                               const float* __restrict__ fw, const float* __restrict__ fb,
                                               float* __restrict__ out) {
    int b = blockIdx.x * 256 + threadIdx.x;
    int d = dom[b];
    const unsigned short* x = X3 + ((long long)d * BATCH + b) * 64;
    const float* wp = fw + d * 64;
    float acc = fb[d];
#pragma unroll
    for (int k = 0; k < 64; k++) acc += b2f(x[k]) * wp[k];
    out[b] = 1.f / (1.f + __expf(-acc));
}

// ---------------------------------------------------------------------------
extern "C" void kernel_launch(void* const* d_in, const int* in_sizes, int n_in,
                              void* d_out, int out_size, void* d_ws, size_t ws_size,
                              hipStream_t stream) {
    const int B = BATCH, D = NDOM;
    const int dims[4] = {256, 256, 128, 64};

    const int* id_idx = (const int*)d_in[0];
    const int* agn_idx = (const int*)d_in[1];
    const int* dom = (const int*)d_in[2];
    const float* id_t = (const float*)d_in[3];
    const float* agn_t = (const float*)d_in[4];
    const float *mlpW[3], *mlpb[3], *bng[3], *bnb[3], *gW1[3], *gb1[3], *gW2[3], *gb2[3];
    for (int i = 0; i < 3; i++) {
        int b0 = 5 + i * 8;
        mlpW[i] = (const float*)d_in[b0 + 0];
        mlpb[i] = (const float*)d_in[b0 + 1];
        bng[i]  = (const float*)d_in[b0 + 2];
        bnb[i]  = (const float*)d_in[b0 + 3];
        gW1[i]  = (const float*)d_in[b0 + 4];
        gb1[i]  = (const float*)d_in[b0 + 5];
        gW2[i]  = (const float*)d_in[b0 + 6];
        gb2[i]  = (const float*)d_in[b0 + 7];
    }
    const float* finW = (const float*)d_in[29];
    const float* finb = (const float*)d_in[30];

    // ---- workspace layout (recomputed identically every call) ----
    char* wsc = (char*)d_ws;
    size_t off = 0;
    auto alloc = [&](size_t bytes) -> char* {
        char* p = wsc + off;
        off = (off + bytes + 255) & ~(size_t)255;
        return p;
    };

    struct { const float* src; int K, N; } mats[9] = {
        {mlpW[0], 256, 256}, {gW1[0], 256, 256}, {gW2[0], 256, 256},
        {mlpW[1], 256, 128}, {gW1[1], 256, 128}, {gW2[1], 128, 128},
        {mlpW[2], 128, 64},  {gW1[2], 256, 64},  {gW2[2], 64, 64}};
    unsigned pfx[10];
    pfx[0] = 0;
    for (int j = 0; j < 9; j++) pfx[j + 1] = pfx[j] + 4u * mats[j].K * mats[j].N;

    unsigned short* wt = (unsigned short*)alloc((size_t)pfx[9] * 2);
    unsigned short* gin = (unsigned short*)alloc((size_t)B * 256 * 2);
    float* stats = (float*)alloc((size_t)3 * 2 * D * 256 * 4);  // per layer: gsum, gssq
    float* murs  = (float*)alloc((size_t)3 * 2 * D * 256 * 4);  // per layer: mu, rs
    unsigned short* G = (unsigned short*)alloc((size_t)D * B * 256 * 2);

    // h_pre precision: fp32 if workspace allows (better BN accuracy), else bf16 in-place
    size_t need32 = (size_t)D * B * 256 * 4 + (size_t)D * B * 128 * 4 +
                    (size_t)D * B * 256 * 2 + (size_t)D * B * 128 * 2 + 4096;
    int hf32 = (ws_size > off) && ((ws_size - off) >= need32);

    char *H0, *H1;
    unsigned short *Xb0, *Xb1;
    if (hf32) {
        H0 = alloc((size_t)D * B * 256 * 4);
        H1 = alloc((size_t)D * B * 128 * 4);
        Xb0 = (unsigned short*)alloc((size_t)D * B * 256 * 2);
        Xb1 = (unsigned short*)alloc((size_t)D * B * 128 * 2);
    } else {
        H0 = alloc((size_t)D * B * 256 * 2);
        H1 = alloc((size_t)D * B * 128 * 2);
        Xb0 = (unsigned short*)H0;  // mode-2 normalize writes in place (same index, same type)
        Xb1 = (unsigned short*)H1;
    }

    PrepArgs pa;
    for (int j = 0; j < 9; j++) {
        pa.m[j].src = mats[j].src;
        pa.m[j].K = (unsigned)mats[j].K;
        pa.m[j].N = (unsigned)mats[j].N;
        pa.m[j].pfx = pfx[j];
        pa.m[j].total = 4u * mats[j].K * mats[j].N;
    }
    pa.stats = stats;
    pa.statsN = 3 * 2 * D * 256;
    pa.grand = pfx[9];

    prep_k<<<dim3((pfx[9] + 255) / 256), dim3(256), 0, stream>>>(pa, wt);
    embed_k<<<dim3(B * 16 / 256), dim3(256), 0, stream>>>(id_idx, agn_idx, id_t, agn_t, gin);

    const unsigned short* Xcur = gin;
    long long xds = 0;
    char* Hbuf[3] = {H0, H1, H0};
    unsigned short* Xout[3] = {Xb0, Xb1, Xb0};

    for (int i = 0; i < 3; i++) {
        const int K = dims[i], N = dims[i + 1];
        float* gsum_i = stats + (size_t)i * 2 * D * 256;
        float* gssq_i = gsum_i + D * 256;
        float* mu_i = murs + (size_t)i * 2 * D * 256;
        float* rs_i = mu_i + D * 256;
        unsigned short* wtM  = wt + pfx[i * 3 + 0];
        unsigned short* wtG1 = wt + pfx[i * 3 + 1];
        unsigned short* wtG2 = wt + pfx[i * 3 + 2];
        dim3 grid(B / TM, N / TN, D);

        // A: h_pre = X @ mlp_W + b, with BN stat accumulation
        gemm_ep<<<grid, 256, 0, stream>>>(Xcur, xds, wtM, mlpb[i], (void*)Hbuf[i],
                                          N, K, 0, hf32, nullptr, nullptr, nullptr, nullptr, nullptr,
                                          gsum_i, gssq_i);
        bn_finalize<<<(D * N + 255) / 256, 256, 0, stream>>>(gsum_i, gssq_i, mu_i, rs_i, D * N, 1.f / B);
        // G1: g1 = relu(gate_in @ gW1 + gb1)
        gemm_ep<<<grid, 256, 0, stream>>>(gin, 0, wtG1, gb1[i], (void*)G,
                                          N, 256, 1, 0, nullptr, nullptr, nullptr, nullptr, nullptr,
                                          nullptr, nullptr);
        // C: gate = 2*sigmoid(g1 @ gW2 + gb2); X_next = relu(BN(h_pre)) * gate
        gemm_ep<<<grid, 256, 0, stream>>>(G, (long long)B * N, wtG2, gb2[i], (void*)Xout[i],
                                          N, N, 2, hf32, (const void*)Hbuf[i], mu_i, rs_i, bng[i], bnb[i],
                                          nullptr, nullptr);
        Xcur = Xout[i];
        xds = (long long)B * N;
    }

    final_k<<<dim3(B / 256), dim3(256), 0, stream>>>(Xout[2], dom, finW, finb, (float*)d_out);
}

// Round 2
// 506.700 us; speedup vs baseline: 1.1054x; 1.1054x over previous
//
#include <hip/hip_runtime.h>

// PPNet forward, round 2: per-layer fully-fused kernel.
// stats_k: h_pre = X@Wm (bf16 MFMA, fp32 acc) -> per-(d,n) sum/ssq (no store).
// fin_k:   SC = rsqrt(var+eps)*gamma, SH = beta - mean*SC  (mlp bias cancels in BN).
// fused_k: g1=relu(gin@W1+b1) -> LDS; gate=2*sigmoid(g1@W2+b2) in regs;
//          h=X@Wm recomputed in fp32 regs; out = relu(h*SC+SH)*gate -> X_next.
//          Layer 2 also folds the final dot+sigmoid+domain select.
// K-loops are barrier-free: A from XOR-swizzled LDS (2-way = free), B (weights,
// L2-resident) loaded per-kstep directly from global as coalesced 16B frags.

typedef __attribute__((ext_vector_type(8))) short short8;
typedef __attribute__((ext_vector_type(4))) float floatx4;

#define BATCH 32768
#define NDOM 4
#define TM 64

__device__ __forceinline__ unsigned short f2b(float f) {
    unsigned u = __float_as_uint(f);
    u += 0x7fffu + ((u >> 16) & 1u);  // round-to-nearest-even
    return (unsigned short)(u >> 16);
}
__device__ __forceinline__ float b2f(unsigned short h) {
    return __uint_as_float(((unsigned)h) << 16);
}

// ---------------------------------------------------------------------------
// Weight prep: fp32 (D,K,N) -> bf16 (D,N,K) packed; zero stat accumulators.
struct MatDesc { const float* src; unsigned K, N, pfx, total; };
struct PrepArgs { MatDesc m[9]; float* stats; unsigned statsN; unsigned grand; };

__global__ __launch_bounds__(256) void prep_k(PrepArgs a, unsigned short* __restrict__ wt) {
    unsigned e = blockIdx.x * 256 + threadIdx.x;
    if (e < a.statsN) a.stats[e] = 0.f;
    if (e >= a.grand) return;
    int j = 0;
    while (j < 8 && e >= a.m[j].pfx + a.m[j].total) j++;
    const unsigned K = a.m[j].K, N = a.m[j].N;
    const unsigned local = e - a.m[j].pfx;
    const unsigned kn = K * N;
    const unsigned d = local / kn;
    const unsigned r2 = local - d * kn;
    const unsigned n = r2 / K;
    const unsigned k = r2 - n * K;
    wt[e] = f2b(a.m[j].src[((long long)d * K + k) * N + n]);
}

// ---------------------------------------------------------------------------
__global__ __launch_bounds__(256) void embed_k(const int* __restrict__ idi, const int* __restrict__ agi,
                                               const float* __restrict__ idt, const float* __restrict__ agt,
                                               unsigned short* __restrict__ gin) {
    int t = blockIdx.x * 256 + threadIdx.x;  // B*16 threads, one per (b, 16-elem slot)
    int b = t >> 4, slot = t & 15;
    int f = slot & 7;
    const int* ip = (slot < 8) ? idi : agi;
    const float* tab = (slot < 8) ? idt : agt;
    int ix = ip[b * 8 + f];
    const float* src = tab + ((long long)f * 100000 + ix) * 16;
    unsigned short tmp[16];
#pragma unroll
    for (int j = 0; j < 16; j++) tmp[j] = f2b(src[j]);
    unsigned short* dst = gin + (long long)b * 256 + slot * 16;
    *(uint4*)dst = *(const uint4*)tmp;
    *(uint4*)(dst + 8) = *(const uint4*)(tmp + 8);
}

// ---------------------------------------------------------------------------
// Stats-only GEMM: acc = X@Wm (no bias), accumulate per-(d,n) sum & sumsq.
template <int N, int KX>
__global__ __launch_bounds__(256, 2) void stats_k(
    const unsigned short* __restrict__ X, int ginMode,
    const unsigned short* __restrict__ Wm,
    float* __restrict__ gsum, float* __restrict__ gssq) {
    constexpr int GX = KX / 8;
    constexpr int NW = N / 4, CT = NW / 16;
    __shared__ __align__(16) unsigned short tA[TM * KX];
    const int t = threadIdx.x;
    const int d = blockIdx.y;
    const int m0 = blockIdx.x * TM;
    const unsigned short* Xp = X + ((long long)(ginMode ? 0 : d * BATCH) + m0) * KX;
#pragma unroll
    for (int r = 0; r < TM * GX / 256; r++) {
        int idx = r * 256 + t;
        int m = idx / GX, j = idx % GX;
        uint4 v = *(const uint4*)(Xp + (long long)m * KX + j * 8);
        *(uint4*)&tA[(m * GX + (j ^ (m & 7))) * 8] = v;
    }
    __syncthreads();
    const int w = t >> 6, lane = t & 63, lrow = lane & 15, lq = lane >> 4;
    const int n0w = w * NW;
    const unsigned short* Wp = Wm + ((long long)d * N + n0w) * KX;
    floatx4 acc[4][CT];
#pragma unroll
    for (int rt = 0; rt < 4; rt++)
#pragma unroll
        for (int ct = 0; ct < CT; ct++) acc[rt][ct] = (floatx4)(0.f);
#pragma unroll
    for (int k0 = 0; k0 < KX; k0 += 32) {
        short8 a[4], b[CT];
#pragma unroll
        for (int rt = 0; rt < 4; rt++) {
            int m = rt * 16 + lrow;
            a[rt] = *(const short8*)&tA[(m * GX + (((k0 >> 3) | lq) ^ (m & 7))) * 8];
        }
#pragma unroll
        for (int ct = 0; ct < CT; ct++)
            b[ct] = *(const short8*)(Wp + (long long)(ct * 16 + lrow) * KX + k0 + lq * 8);
#pragma unroll
        for (int rt = 0; rt < 4; rt++)
#pragma unroll
            for (int ct = 0; ct < CT; ct++)
                acc[rt][ct] = __builtin_amdgcn_mfma_f32_16x16x32_bf16(a[rt], b[ct], acc[rt][ct], 0, 0, 0);
    }
#pragma unroll
    for (int ct = 0; ct < CT; ct++) {
        float s = 0.f, ss = 0.f;
#pragma unroll
        for (int rt = 0; rt < 4; rt++)
#pragma unroll
            for (int r = 0; r < 4; r++) { float v = acc[rt][ct][r]; s += v; ss += v * v; }
        s += __shfl_down(s, 32); ss += __shfl_down(ss, 32);
        s += __shfl_down(s, 16); ss += __shfl_down(ss, 16);
        if (lane < 16) {
            atomicAdd(&gsum[d * N + n0w + ct * 16 + lane], s);
            atomicAdd(&gssq[d * N + n0w + ct * 16 + lane], ss);
        }
    }
}

// ---------------------------------------------------------------------------
__global__ void fin_k(const float* __restrict__ gsum, const float* __restrict__ gssq,
                      const float* __restrict__ gma, const float* __restrict__ bta,
                      float* __restrict__ SC, float* __restrict__ SH, int total, float invB) {
    int i = blockIdx.x * blockDim.x + threadIdx.x;
    if (i >= total) return;
    float ma = gsum[i] * invB;
    float var = gssq[i] * invB - ma * ma;
    float rs = rsqrtf(var + 1e-5f);
    float sc = rs * gma[i];
    SC[i] = sc;
    SH[i] = bta[i] - ma * sc;
}

// ---------------------------------------------------------------------------
// Fully fused layer kernel. gin tile LDS-resident for g1; restaged with Xh for
// the h-phase (layers 1,2). gate held in registers (C-layout aligned with h).
template <int N, int KX, bool RESTAGE, bool FINAL>
__global__ __launch_bounds__(256, 2) void fused_k(
    const unsigned short* __restrict__ gin,
    const unsigned short* __restrict__ Xh,
    const unsigned short* __restrict__ W1,   // [d][N][256]
    const unsigned short* __restrict__ W2,   // [d][N][N]
    const unsigned short* __restrict__ Wm,   // [d][N][KX]
    const float* __restrict__ gb1, const float* __restrict__ gb2,
    const float* __restrict__ SC, const float* __restrict__ SH,
    unsigned short* __restrict__ Xn,
    const int* __restrict__ dom, const float* __restrict__ fw,
    const float* __restrict__ fb, float* __restrict__ outp) {
    constexpr int GG = N / 8;
    constexpr int GX = KX / 8;
    constexpr int NW = N / 4, CT = NW / 16;
    __shared__ __align__(16) unsigned short tA[TM * 256];
    __shared__ __align__(16) unsigned short g1b[TM * N];
    const int t = threadIdx.x;
    const int d = blockIdx.y;
    const int m0 = blockIdx.x * TM;
    const int w = t >> 6, lane = t & 63, lrow = lane & 15, lq = lane >> 4;
    const int n0w = w * NW;

    {  // stage gin tile (K=256), XOR-swizzled granules
        const unsigned short* Gp = gin + (long long)m0 * 256;
#pragma unroll
        for (int r = 0; r < 8; r++) {
            int idx = r * 256 + t;
            int m = idx >> 5, j = idx & 31;
            uint4 v = *(const uint4*)(Gp + (long long)m * 256 + j * 8);
            *(uint4*)&tA[((m << 5) + (j ^ (m & 7))) * 8] = v;
        }
    }
    __syncthreads();

    // ---- phase g1: relu(gin @ W1 + b1) -> g1b (bf16, swizzled row-major)
    floatx4 acc1[4][CT];
#pragma unroll
    for (int rt = 0; rt < 4; rt++)
#pragma unroll
        for (int ct = 0; ct < CT; ct++) acc1[rt][ct] = (floatx4)(0.f);
    const unsigned short* W1p = W1 + ((long long)d * N + n0w) * 256;
#pragma unroll
    for (int k0 = 0; k0 < 256; k0 += 32) {
        short8 a[4], b[CT];
#pragma unroll
        for (int rt = 0; rt < 4; rt++) {
            int m = rt * 16 + lrow;
            a[rt] = *(const short8*)&tA[((m << 5) + (((k0 >> 3) | lq) ^ (m & 7))) * 8];
        }
#pragma unroll
        for (int ct = 0; ct < CT; ct++)
            b[ct] = *(const short8*)(W1p + (long long)(ct * 16 + lrow) * 256 + k0 + lq * 8);
#pragma unroll
        for (int rt = 0; rt < 4; rt++)
#pragma unroll
            for (int ct = 0; ct < CT; ct++)
                acc1[rt][ct] = __builtin_amdgcn_mfma_f32_16x16x32_bf16(a[rt], b[ct], acc1[rt][ct], 0, 0, 0);
    }
#pragma unroll
    for (int ct = 0; ct < CT; ct++) {
        int n = n0w + ct * 16 + lrow;
        float bs = gb1[d * N + n];
        int jj = n >> 3, sub = n & 7;
#pragma unroll
        for (int rt = 0; rt < 4; rt++)
#pragma unroll
            for (int r = 0; r < 4; r++) {
                int m = rt * 16 + lq * 4 + r;
                g1b[(m * GG + (jj ^ (m & 7))) * 8 + sub] = f2b(fmaxf(acc1[rt][ct][r] + bs, 0.f));
            }
    }
    __syncthreads();  // g1b writes -> g2 reads

    // ---- phase g2: gate = 2*sigmoid(g1 @ W2 + b2), kept in registers
    floatx4 acc2[4][CT];
#pragma unroll
    for (int rt = 0; rt < 4; rt++)
#pragma unroll
        for (int ct = 0; ct < CT; ct++) acc2[rt][ct] = (floatx4)(0.f);
    const unsigned short* W2p = W2 + ((long long)d * N + n0w) * N;
#pragma unroll
    for (int k0 = 0; k0 < N; k0 += 32) {
        short8 a[4], b[CT];
#pragma unroll
        for (int rt = 0; rt < 4; rt++) {
            int m = rt * 16 + lrow;
            a[rt] = *(const short8*)&g1b[(m * GG + (((k0 >> 3) | lq) ^ (m & 7))) * 8];
        }
#pragma unroll
        for (int ct = 0; ct < CT; ct++)
            b[ct] = *(const short8*)(W2p + (long long)(ct * 16 + lrow) * N + k0 + lq * 8);
#pragma unroll
        for (int rt = 0; rt < 4; rt++)
#pragma unroll
            for (int ct = 0; ct < CT; ct++)
                acc2[rt][ct] = __builtin_amdgcn_mfma_f32_16x16x32_bf16(a[rt], b[ct], acc2[rt][ct], 0, 0, 0);
    }
    float gate[4][CT][4];
#pragma unroll
    for (int ct = 0; ct < CT; ct++) {
        int n = n0w + ct * 16 + lrow;
        float bs = gb2[d * N + n];
#pragma unroll
        for (int rt = 0; rt < 4; rt++)
#pragma unroll
            for (int r = 0; r < 4; r++)
                gate[rt][ct][r] = 2.f / (1.f + __expf(-(acc2[rt][ct][r] + bs)));
    }

    if (RESTAGE) {  // overwrite tA with this layer's h-input
        const unsigned short* Xp = Xh + ((long long)d * BATCH + m0) * KX;
#pragma unroll
        for (int r = 0; r < TM * GX / 256; r++) {
            int idx = r * 256 + t;
            int m = idx / GX, j = idx % GX;
            uint4 v = *(const uint4*)(Xp + (long long)m * KX + j * 8);
            *(uint4*)&tA[(m * GX + (j ^ (m & 7))) * 8] = v;
        }
    }
    __syncthreads();  // restage done; also: everyone past g2 (g1b reusable)

    // ---- phase h: acc = X @ Wm (bias cancels in BN)
    floatx4 acch[4][CT];
#pragma unroll
    for (int rt = 0; rt < 4; rt++)
#pragma unroll
        for (int ct = 0; ct < CT; ct++) acch[rt][ct] = (floatx4)(0.f);
    const unsigned short* Wmp = Wm + ((long long)d * N + n0w) * KX;
#pragma unroll
    for (int k0 = 0; k0 < KX; k0 += 32) {
        short8 a[4], b[CT];
#pragma unroll
        for (int rt = 0; rt < 4; rt++) {
            int m = rt * 16 + lrow;
            a[rt] = *(const short8*)&tA[(m * GX + (((k0 >> 3) | lq) ^ (m & 7))) * 8];
        }
#pragma unroll
        for (int ct = 0; ct < CT; ct++)
            b[ct] = *(const short8*)(Wmp + (long long)(ct * 16 + lrow) * KX + k0 + lq * 8);
#pragma unroll
        for (int rt = 0; rt < 4; rt++)
#pragma unroll
            for (int ct = 0; ct < CT; ct++)
                acch[rt][ct] = __builtin_amdgcn_mfma_f32_16x16x32_bf16(a[rt], b[ct], acch[rt][ct], 0, 0, 0);
    }
    // epilogue: X_next = relu(h*SC + SH) * gate -> g1b plain [m][n]
#pragma unroll
    for (int ct = 0; ct < CT; ct++) {
        int n = n0w + ct * 16 + lrow;
        float sc = SC[d * N + n], sh = SH[d * N + n];
#pragma unroll
        for (int rt = 0; rt < 4; rt++)
#pragma unroll
            for (int r = 0; r < 4; r++) {
                int m = rt * 16 + lq * 4 + r;
                float v = fmaxf(acch[rt][ct][r] * sc + sh, 0.f) * gate[rt][ct][r];
                g1b[m * N + n] = f2b(v);
            }
    }
    __syncthreads();

    if (!FINAL) {
        unsigned short* Op = Xn + ((long long)d * BATCH + m0) * N;
#pragma unroll
        for (int r = 0; r < TM * GG / 256; r++) {
            int idx = r * 256 + t;
            int m = idx / GG, j = idx % GG;
            *(uint4*)(Op + (long long)m * N + j * 8) = *(const uint4*)&g1b[(m * GG + j) * 8];
        }
    } else {
        // final: out[b] = sigmoid(X3[b] . finW[d] + finb[d]) where d == dom[b]
        int m = t >> 2, q = t & 3;
        const float* fwp = fw + d * 64;
        float s = 0.f;
#pragma unroll
        for (int k = 0; k < 16; k++) s += b2f(g1b[m * 64 + q * 16 + k]) * fwp[q * 16 + k];
        s += __shfl_down(s, 1);
        s += __shfl_down(s, 2);
        if (q == 0) {
            int b = m0 + m;
            if (dom[b] == d) outp[b] = 1.f / (1.f + __expf(-(s + fb[d])));
        }
    }
}

// ---------------------------------------------------------------------------
extern "C" void kernel_launch(void* const* d_in, const int* in_sizes, int n_in,
                              void* d_out, int out_size, void* d_ws, size_t ws_size,
                              hipStream_t stream) {
    const int B = BATCH, D = NDOM;

    const int* id_idx = (const int*)d_in[0];
    const int* agn_idx = (const int*)d_in[1];
    const int* dom = (const int*)d_in[2];
    const float* id_t = (const float*)d_in[3];
    const float* agn_t = (const float*)d_in[4];
    const float *mlpW[3], *bng[3], *bnb[3], *gW1[3], *gb1[3], *gW2[3], *gb2[3];
    for (int i = 0; i < 3; i++) {
        int b0 = 5 + i * 8;
        mlpW[i] = (const float*)d_in[b0 + 0];
        bng[i] = (const float*)d_in[b0 + 2];
        bnb[i] = (const float*)d_in[b0 + 3];
        gW1[i] = (const float*)d_in[b0 + 4];
        gb1[i] = (const float*)d_in[b0 + 5];
        gW2[i] = (const float*)d_in[b0 + 6];
        gb2[i] = (const float*)d_in[b0 + 7];
    }
    const float* finW = (const float*)d_in[29];
    const float* finb = (const float*)d_in[30];

    char* wsc = (char*)d_ws;
    size_t off = 0;
    auto alloc = [&](size_t bytes) -> char* {
        char* p = wsc + off;
        off = (off + bytes + 255) & ~(size_t)255;
        return p;
    };

    struct { const float* src; int K, N; } mats[9] = {
        {mlpW[0], 256, 256}, {gW1[0], 256, 256}, {gW2[0], 256, 256},
        {mlpW[1], 256, 128}, {gW1[1], 256, 128}, {gW2[1], 128, 128},
        {mlpW[2], 128, 64},  {gW1[2], 256, 64},  {gW2[2], 64, 64}};
    unsigned pfx[10];
    pfx[0] = 0;
    for (int j = 0; j < 9; j++) pfx[j + 1] = pfx[j] + 4u * mats[j].K * mats[j].N;

    unsigned short* wt = (unsigned short*)alloc((size_t)pfx[9] * 2);
    unsigned short* gin = (unsigned short*)alloc((size_t)B * 256 * 2);
    float* stats = (float*)alloc((size_t)3 * 2 * D * 256 * 4);  // per layer: gsum, gssq
    float* scsh = (float*)alloc((size_t)3 * 2 * D * 256 * 4);   // per layer: SC, SH
    unsigned short* X1 = (unsigned short*)alloc((size_t)D * B * 256 * 2);
    unsigned short* X2 = (unsigned short*)alloc((size_t)D * B * 128 * 2);

    PrepArgs pa;
    for (int j = 0; j < 9; j++) {
        pa.m[j].src = mats[j].src;
        pa.m[j].K = (unsigned)mats[j].K;
        pa.m[j].N = (unsigned)mats[j].N;
        pa.m[j].pfx = pfx[j];
        pa.m[j].total = 4u * mats[j].K * mats[j].N;
    }
    pa.stats = stats;
    pa.statsN = 3 * 2 * D * 256;
    pa.grand = pfx[9];

    const float invB = 1.f / (float)B;
    dim3 gs(B / TM, D);

    prep_k<<<dim3((pfx[9] + 255) / 256), 256, 0, stream>>>(pa, wt);
    embed_k<<<dim3(B * 16 / 256), 256, 0, stream>>>(id_idx, agn_idx, id_t, agn_t, gin);

    float* gsum0 = stats + 0 * 2 * D * 256; float* gssq0 = gsum0 + D * 256;
    float* gsum1 = stats + 1 * 2 * D * 256; float* gssq1 = gsum1 + D * 256;
    float* gsum2 = stats + 2 * 2 * D * 256; float* gssq2 = gsum2 + D * 256;
    float* SC0 = scsh + 0 * 2 * D * 256; float* SH0 = SC0 + D * 256;
    float* SC1 = scsh + 1 * 2 * D * 256; float* SH1 = SC1 + D * 256;
    float* SC2 = scsh + 2 * 2 * D * 256; float* SH2 = SC2 + D * 256;

    // ---- layer 0 (K=256 -> N=256)
    stats_k<256, 256><<<gs, 256, 0, stream>>>(gin, 1, wt + pfx[0], gsum0, gssq0);
    fin_k<<<(D * 256 + 255) / 256, 256, 0, stream>>>(gsum0, gssq0, bng[0], bnb[0], SC0, SH0, D * 256, invB);
    fused_k<256, 256, false, false><<<gs, 256, 0, stream>>>(
        gin, gin, wt + pfx[1], wt + pfx[2], wt + pfx[0], gb1[0], gb2[0], SC0, SH0,
        X1, nullptr, nullptr, nullptr, nullptr);

    // ---- layer 1 (K=256 -> N=128)
    stats_k<128, 256><<<gs, 256, 0, stream>>>(X1, 0, wt + pfx[3], gsum1, gssq1);
    fin_k<<<(D * 128 + 255) / 256, 256, 0, stream>>>(gsum1, gssq1, bng[1], bnb[1], SC1, SH1, D * 128, invB);
    fused_k<128, 256, true, false><<<gs, 256, 0, stream>>>(
        gin, X1, wt + pfx[4], wt + pfx[5], wt + pfx[3], gb1[1], gb2[1], SC1, SH1,
        X2, nullptr, nullptr, nullptr, nullptr);

    // ---- layer 2 (K=128 -> N=64), with fused final dot + sigmoid + select
    stats_k<64, 128><<<gs, 256, 0, stream>>>(X2, 0, wt + pfx[6], gsum2, gssq2);
    fin_k<<<(D * 64 + 255) / 256, 256, 0, stream>>>(gsum2, gssq2, bng[2], bnb[2], SC2, SH2, D * 64, invB);
    fused_k<64, 128, true, true><<<gs, 256, 0, stream>>>(
        gin, X2, wt + pfx[7], wt + pfx[8], wt + pfx[6], gb1[2], gb2[2], SC2, SH2,
        nullptr, dom, finW, finb, (float*)d_out);
}